// Round 6
// baseline (525.206 us; speedup 1.0000x reference)
//
#include <hip/hip_runtime.h>

// ---------------------------------------------------------------------------
// SpatialAwareSelfAttention  (B=16, H=W=56, C=512, heads=8, window=4x4)
//
// Round 9: split fragment traffic across LDS + L2 pipes.
//   Diagnosis (R5/R6/R8 all ~26% MfmaUtil): CU retires 0.82 MFMA/cyc but only
//   ~0.083 ds_read_b128/cyc -> any all-LDS schedule is capped at ~26-30%.
//   k_fused: block = 128 tok x 1 head, grid (392,8), 512 thr, 8 waves of
//   M64xN48. A staged via gl2lds (swizzled, dbuf 2x16KB, counted vmcnt(2));
//   B fragments read DIRECT from global (L2-hot 196KB/head panel; quads give
//   64B-contiguous per row). LDS reads 4/12 per kk (cap ~60%); LDS total
//   64KB (attn 2 sets x 32KB alias A-dbuf) -> 2 blocks/CU, 4 waves/SIMD.
//   k_gemm_proj: LDS-free direct GEMM (both operands from L2, no barriers).
//   k_window_pool: 16B stores, 4 windows/block.
// ---------------------------------------------------------------------------

using bf16x8 = __attribute__((ext_vector_type(8))) short;
using f32x4  = __attribute__((ext_vector_type(4))) float;

#define SCALE 0.044194173824159216f   // 512^-0.5 (full C, per reference)

__device__ __forceinline__ unsigned short f2bf(float f) {
    union { float f; unsigned u; } v; v.f = f;
    unsigned u = v.u;
    return (unsigned short)((u + 0x7fffu + ((u >> 16) & 1u)) >> 16);
}

__device__ __forceinline__ unsigned pk2(float a, float b) {
    return (unsigned)f2bf(a) | ((unsigned)f2bf(b) << 16);
}

__device__ __forceinline__ void gl2lds16(const unsigned short* g, unsigned short* l) {
    __builtin_amdgcn_global_load_lds(
        (const __attribute__((address_space(1))) void*)g,
        (__attribute__((address_space(3))) void*)l, 16, 0, 0);
}

// ---- K0a: weight conversion/repack ----------------------------------------
__global__ void k_prep_weights(const float* __restrict__ wqkv_h,
                               const float* __restrict__ wqkv_l,
                               const float* __restrict__ wproj,
                               unsigned short* __restrict__ WH,
                               unsigned short* __restrict__ WLV,
                               unsigned short* __restrict__ WP1,
                               unsigned short* __restrict__ WP2) {
    int i = blockIdx.x * 256 + threadIdx.x;
    if (i < 786432) {
        WH[i] = f2bf(wqkv_h[i]);              // [1536][512] row-major
    } else {
        int j = i - 786432;
        int r = j >> 18;
        int t = j & 262143;
        int n = t >> 9, k = t & 511;
        if (r == 0)      WLV[t] = f2bf(wqkv_l[(1024 + n) * 512 + k]); // v-rows
        else if (r == 1) WP1[t] = f2bf(wproj[n * 1024 + k]);
        else             WP2[t] = f2bf(wproj[n * 1024 + 512 + k]);
    }
}

// ---- K0b: window partition + pooling, 16B stores, 4 windows/block ---------
__global__ void k_window_pool(const float* __restrict__ x,
                              unsigned short* __restrict__ XW,
                              unsigned short* __restrict__ XAVG) {
    int win = blockIdx.x * 4 + (threadIdx.x >> 6);
    int g = threadIdx.x & 63;          // channel-group of 8
    int c = g * 8;
    int b = win / 196, rem = win % 196, wh = rem / 14, ww = rem % 14;
    float s0 = 0.f, s1 = 0.f, s2 = 0.f, s3 = 0.f, s4 = 0.f, s5 = 0.f, s6 = 0.f, s7 = 0.f;
    #pragma unroll
    for (int t = 0; t < 16; ++t) {
        int row = (b * 56 + wh * 4 + (t >> 2)) * 56 + ww * 4 + (t & 3);
        const float* p = &x[(size_t)row * 512 + c];
        float4 v0 = *(const float4*)p;
        float4 v1 = *(const float4*)(p + 4);
        uint4 pk;
        pk.x = pk2(v0.x, v0.y); pk.y = pk2(v0.z, v0.w);
        pk.z = pk2(v1.x, v1.y); pk.w = pk2(v1.z, v1.w);
        *(uint4*)&XW[(size_t)(win * 16 + t) * 512 + c] = pk;
        s0 += v0.x; s1 += v0.y; s2 += v0.z; s3 += v0.w;
        s4 += v1.x; s5 += v1.y; s6 += v1.z; s7 += v1.w;
    }
    uint4 pa;
    pa.x = pk2(s0 * 0.0625f, s1 * 0.0625f);
    pa.y = pk2(s2 * 0.0625f, s3 * 0.0625f);
    pa.z = pk2(s4 * 0.0625f, s5 * 0.0625f);
    pa.w = pk2(s6 * 0.0625f, s7 * 0.0625f);
    *(uint4*)&XAVG[(size_t)win * 512 + c] = pa;
}

// ---- K1: small K=512 GEMM C = A @ B^T, wave tile 16 x (NT*16) -------------
template <int NT>
__global__ void k_gemm512(const unsigned short* __restrict__ A,
                          const unsigned short* __restrict__ Bw,
                          unsigned short* __restrict__ outB,
                          float* __restrict__ outF,
                          const float* __restrict__ bias) {
    int wave = threadIdx.x >> 6, lane = threadIdx.x & 63;
    int quad = lane >> 4, l16 = lane & 15;
    int m0 = blockIdx.x * 64 + wave * 16;
    int n0 = blockIdx.y * (NT * 16);
    f32x4 acc[NT] = {};
    const unsigned short* arow = A + (size_t)(m0 + l16) * 512 + quad * 8;
    for (int kk = 0; kk < 16; ++kk) {
        bf16x8 a = *(const bf16x8*)(arow + kk * 32);
        #pragma unroll
        for (int nt = 0; nt < NT; ++nt) {
            bf16x8 b = *(const bf16x8*)(Bw + (size_t)(n0 + nt * 16 + l16) * 512 + kk * 32 + quad * 8);
            acc[nt] = __builtin_amdgcn_mfma_f32_16x16x32_bf16(a, b, acc[nt], 0, 0, 0);
        }
    }
    #pragma unroll
    for (int nt = 0; nt < NT; ++nt) {
        int col = n0 + nt * 16 + l16;
        float bv = (bias != nullptr) ? bias[col] : 0.f;
        #pragma unroll
        for (int r = 0; r < 4; ++r) {
            int row = m0 + quad * 4 + r;
            if (outF != nullptr) outF[(size_t)row * 512 + col] = acc[nt][r] + bv;
            else                 outB[(size_t)row * 512 + col] = f2bf(acc[nt][r]);
        }
    }
}

// ---- K2: fused qkv GEMM (128x192x512) + window attention ------------------
// grid (392, 8) XCD-remapped; 512 threads, 8 waves = mh(0,1) x nq(0..3).
// Wave tile M64 x N48. A: LDS-staged (swizzled dbuf, counted vmcnt).
// B: direct global fragment loads (L2-hot per-head weight panel).
__global__ void __launch_bounds__(512, 4) k_fused(const unsigned short* __restrict__ XW,
                                                  const unsigned short* __restrict__ WH,
                                                  unsigned short* __restrict__ XH) {
    __shared__ __align__(16) char smem[65536];
    // A dbuf: buf b at b*16384 : [128][64] shorts (16 KB each)
    // attention (alias, after K-loop): set s at s*32768:
    //   qs [64][72] 9216 | ks [64][72] 9216 | vts [64][80] 10240 | Ps [4][16][32] 4096

    const int tid  = threadIdx.x;
    const int wave = tid >> 6, lane = tid & 63;
    const int quad = lane >> 4, l16 = lane & 15;
    const int mh = wave >> 2, nq = wave & 3;

    // bijective XCD remap (3136 = 8*392): heads of a token-panel stay on one
    // XCD -> 8-head weight set (1.57 MB) + XW panel pinned in that XCD's L2.
    int id   = blockIdx.y * 392 + blockIdx.x;
    int w_   = (id & 7) * 392 + (id >> 3);
    int tb   = w_ >> 3, head = w_ & 7;
    const int m0 = tb * 128;

    // A staging map (rule #21: linear gl2lds dest, inverse-swizzled global
    // src, swizzled ds_read). [128 rows][8 units of 16B]; unit u holds
    // global unit (u&7)^(row&7). 1024 units / 512 thr = 2 per thread.
    int aof[2];
    #pragma unroll
    for (int i = 0; i < 2; ++i) {
        int u = i * 512 + tid;
        int n = u >> 3;
        int gu = (u & 7) ^ (n & 7);
        aof[i] = (m0 + n) * 512 + gu * 8;
    }
    // B direct bases: col n = nq*48 + j*16 + l16; 16-col blocks never cross a
    // 64-col qkv section, so sec = cb>>6 is uniform per j.
    const unsigned short* bp[3];
    #pragma unroll
    for (int j = 0; j < 3; ++j) {
        int cb = nq * 48 + j * 16;
        int row = (cb >> 6) * 512 + head * 64 + (cb & 63) + l16;
        bp[j] = WH + (size_t)row * 512 + quad * 8;
    }

    unsigned short* const bufA[2] = { (unsigned short*)smem,
                                      (unsigned short*)(smem + 16384) };
    f32x4 acc[4][3] = {};
    const int sx = l16 & 7;

    // prologue: stage A chunk 0 (2 gl2lds/thread in flight)
    #pragma unroll
    for (int i = 0; i < 2; ++i)
        gl2lds16(XW + aof[i], bufA[0] + (i * 512 + wave * 64) * 8);

    #pragma unroll
    for (int ch = 0; ch < 8; ++ch) {
        // B fragments for chunk ch FIRST (so vmcnt(2) retires them + stage(ch))
        bf16x8 b[2][3];
        #pragma unroll
        for (int kk = 0; kk < 2; ++kk)
            #pragma unroll
            for (int j = 0; j < 3; ++j)
                b[kk][j] = *(const bf16x8*)(bp[j] + ch * 64 + kk * 32);
        // stage A chunk ch+1 into the other buffer (stays in flight)
        if (ch < 7) {
            unsigned short* An = bufA[(ch + 1) & 1];
            #pragma unroll
            for (int i = 0; i < 2; ++i)
                gl2lds16(XW + aof[i] + (ch + 1) * 64, An + (i * 512 + wave * 64) * 8);
        }
        // retire B(ch) + stage(ch); leave stage(ch+1)'s 2 loads in flight
        if (ch < 7) asm volatile("s_waitcnt vmcnt(2)" ::: "memory");
        else        asm volatile("s_waitcnt vmcnt(0)" ::: "memory");
        __builtin_amdgcn_s_barrier();

        unsigned short* As = bufA[ch & 1];
        #pragma unroll
        for (int kk = 0; kk < 2; ++kk) {
            int su = ((kk * 4 + quad) ^ sx) * 8;
            bf16x8 a[4];
            #pragma unroll
            for (int mf = 0; mf < 4; ++mf)
                a[mf] = *(const bf16x8*)&As[(mh * 64 + mf * 16 + l16) * 64 + su];
            #pragma unroll
            for (int mf = 0; mf < 4; ++mf)
                #pragma unroll
                for (int j = 0; j < 3; ++j)
                    acc[mf][j] = __builtin_amdgcn_mfma_f32_16x16x32_bf16(a[mf], b[kk][j], acc[mf][j], 0, 0, 0);
        }
        // all LDS reads of this buffer done before stage(ch+2) overwrites it
        asm volatile("s_waitcnt lgkmcnt(0)" ::: "memory");
        __builtin_amdgcn_s_barrier();
    }

    // ---- scatter q/k/v^T into attention LDS (aliases A-dbuf) --------------
    {
        char* att = smem + mh * 32768;
        unsigned short* qs  = (unsigned short*)att;
        unsigned short* ks  = (unsigned short*)(att + 9216);
        unsigned short* vts = (unsigned short*)(att + 18432);
        #pragma unroll
        for (int j = 0; j < 3; ++j) {
            int cb = nq * 48 + j * 16;          // 16-aligned col in 0..176
            #pragma unroll
            for (int mf = 0; mf < 4; ++mf) {
                #pragma unroll
                for (int r = 0; r < 4; ++r) {
                    int tok = mf * 16 + quad * 4 + r;   // set-local token 0..63
                    unsigned short hv = f2bf(acc[mf][j][r]);
                    if (cb < 64)       qs[tok * 72 + cb + l16] = hv;
                    else if (cb < 128) ks[tok * 72 + (cb - 64) + l16] = hv;
                    else               vts[(cb - 128 + l16) * 80 + tok] = hv;
                }
            }
        }
    }
    __syncthreads();

    // attention: wave handles window nq of set mh (8 windows, 8 waves).
    char* att = smem + mh * 32768;
    unsigned short* qs  = (unsigned short*)att;
    unsigned short* ks  = (unsigned short*)(att + 9216);
    unsigned short* vts = (unsigned short*)(att + 18432);
    unsigned short* Ps  = (unsigned short*)(att + 28672);
    const int t0 = nq * 16;

    // re-zero pads (wave-local consumers):
    // vts token-cols 64..79 read only by window 3's PV -> nq==3 zeroes them.
    if (nq == 3) {
        #pragma unroll
        for (int i = 0; i < 16; ++i) vts[lane * 80 + 64 + i] = 0;
    }
    {
        int prow = lane >> 2, pc = 16 + (lane & 3) * 4;
        #pragma unroll
        for (int i = 0; i < 4; ++i) Ps[nq * 512 + prow * 32 + pc + i] = 0;
    }

    // S = (q @ k^T) * scale
    f32x4 sacc = {};
    {
        bf16x8 a0 = *(const bf16x8*)&qs[(t0 + l16) * 72 + quad * 8];
        bf16x8 b0 = *(const bf16x8*)&ks[(t0 + l16) * 72 + quad * 8];
        sacc = __builtin_amdgcn_mfma_f32_16x16x32_bf16(a0, b0, sacc, 0, 0, 0);
        bf16x8 a1 = *(const bf16x8*)&qs[(t0 + l16) * 72 + 32 + quad * 8];
        bf16x8 b1 = *(const bf16x8*)&ks[(t0 + l16) * 72 + 32 + quad * 8];
        sacc = __builtin_amdgcn_mfma_f32_16x16x32_bf16(a1, b1, sacc, 0, 0, 0);
    }
    // in-register softmax: row r lives across the quad's 16 lanes
    float p[4];
    #pragma unroll
    for (int r = 0; r < 4; ++r) {
        float v = sacc[r] * SCALE;
        float m = v;
        m = fmaxf(m, __shfl_xor(m, 1));
        m = fmaxf(m, __shfl_xor(m, 2));
        m = fmaxf(m, __shfl_xor(m, 4));
        m = fmaxf(m, __shfl_xor(m, 8));
        float e = __expf(v - m);
        float sm = e;
        sm += __shfl_xor(sm, 1);
        sm += __shfl_xor(sm, 2);
        sm += __shfl_xor(sm, 4);
        sm += __shfl_xor(sm, 8);
        p[r] = e / sm;
    }
    #pragma unroll
    for (int r = 0; r < 4; ++r)
        Ps[nq * 512 + (quad * 4 + r) * 32 + l16] = f2bf(p[r]);

    // y = P @ v (K=16 padded to 32; pad-P is zero)
    bf16x8 pa = *(const bf16x8*)&Ps[nq * 512 + l16 * 32 + quad * 8];
    #pragma unroll
    for (int nt = 0; nt < 4; ++nt) {
        f32x4 y = {};
        bf16x8 bv = *(const bf16x8*)&vts[(nt * 16 + l16) * 80 + t0 + quad * 8];
        y = __builtin_amdgcn_mfma_f32_16x16x32_bf16(pa, bv, y, 0, 0, 0);
        #pragma unroll
        for (int r = 0; r < 4; ++r)
            XH[(size_t)(m0 + mh * 64 + t0 + quad * 4 + r) * 512 + head * 64 + nt * 16 + l16] = f2bf(y[r]);
    }
}

// ---- K3: out = XH @ WP1^T + G[win] — LDS-free direct GEMM -----------------
// grid (392, 4), XCD-remapped; 128x128 block, wave 64x64, both operands
// straight from global (XH/WP1 are L2/L3-hot); zero barriers.
__global__ void __launch_bounds__(256, 4) k_gemm_proj(const unsigned short* __restrict__ XH,
                                                      const unsigned short* __restrict__ WP1,
                                                      const float* __restrict__ G,
                                                      float* __restrict__ out) {
    const int wave = threadIdx.x >> 6, lane = threadIdx.x & 63;
    const int quad = lane >> 4, l16 = lane & 15;

    // bijective XCD remap (1568 = 8*196)
    int id = blockIdx.y * 392 + blockIdx.x;
    int s  = id >> 3;
    int xb = (id & 7) * 49 + (s >> 2);
    int yb = s & 3;
    const int m0 = xb * 128, n0 = yb * 128;
    const int wm = (wave >> 1) * 64;   // wave row offset (2x2 wave grid)
    const int wn = (wave & 1) * 64;    // wave col offset

    const unsigned short* ap[4];
    const unsigned short* bp[4];
    #pragma unroll
    for (int i = 0; i < 4; ++i) {
        ap[i] = XH  + (size_t)(m0 + wm + i * 16 + l16) * 512 + quad * 8;
        bp[i] = WP1 + (size_t)(n0 + wn + i * 16 + l16) * 512 + quad * 8;
    }

    f32x4 acc[4][4] = {};

    #pragma unroll 4
    for (int kk = 0; kk < 16; ++kk) {
        bf16x8 a[4], b[4];
        #pragma unroll
        for (int mf = 0; mf < 4; ++mf) a[mf] = *(const bf16x8*)(ap[mf] + kk * 32);
        #pragma unroll
        for (int j = 0; j < 4; ++j)    b[j]  = *(const bf16x8*)(bp[j] + kk * 32);
        #pragma unroll
        for (int mf = 0; mf < 4; ++mf)
            #pragma unroll
            for (int j = 0; j < 4; ++j)
                acc[mf][j] = __builtin_amdgcn_mfma_f32_16x16x32_bf16(a[mf], b[j], acc[mf][j], 0, 0, 0);
    }

    #pragma unroll
    for (int mf = 0; mf < 4; ++mf) {
        #pragma unroll
        for (int r = 0; r < 4; ++r) {
            int tl  = wm + mf * 16 + quad * 4 + r;   // 0..127
            int gt  = m0 + tl;                        // global token
            int win = gt >> 4, tw = gt & 15;
            int bb = win / 196, rem = win % 196;
            int wh = rem / 14, ww = rem % 14;
            int orow = (bb * 56 + wh * 4 + (tw >> 2)) * 56 + ww * 4 + (tw & 3);
            #pragma unroll
            for (int j = 0; j < 4; ++j) {
                int ncol = n0 + wn + j * 16 + l16;
                out[(size_t)orow * 512 + ncol] = acc[mf][j][r] + G[(size_t)win * 512 + ncol];
            }
        }
    }
}

// ---------------------------------------------------------------------------
extern "C" void kernel_launch(void* const* d_in, const int* in_sizes, int n_in,
                              void* d_out, int out_size, void* d_ws, size_t ws_size,
                              hipStream_t stream) {
    const float* x      = (const float*)d_in[0];
    const float* wqkv_h = (const float*)d_in[1];
    const float* wqkv_l = (const float*)d_in[2];
    const float* wproj  = (const float*)d_in[3];
    const float* bproj  = (const float*)d_in[4];
    float* out = (float*)d_out;

    char* ws = (char*)d_ws;
    unsigned short* WH   = (unsigned short*)(ws + 0);         // 1536*512 bf16
    unsigned short* WLV  = (unsigned short*)(ws + 1572864);   // 512*512
    unsigned short* WP1  = (unsigned short*)(ws + 2097152);   // 512*512
    unsigned short* WP2  = (unsigned short*)(ws + 2621440);   // 512*512
    unsigned short* XW   = (unsigned short*)(ws + 3145728);   // 50176*512
    unsigned short* XAVG = (unsigned short*)(ws + 54525952);  // 3136*512
    unsigned short* VL   = (unsigned short*)(ws + 57737216);  // 3136*512
    float*          G    = (float*)(ws + 60948480);           // 3136*512 f32
    unsigned short* XH   = (unsigned short*)(ws + 67371008);  // 50176*512

    k_prep_weights<<<dim3(6144), dim3(256), 0, stream>>>(wqkv_h, wqkv_l, wproj, WH, WLV, WP1, WP2);
    k_window_pool<<<dim3(784), dim3(256), 0, stream>>>(x, XW, XAVG);
    k_gemm512<2><<<dim3(49, 16), dim3(256), 0, stream>>>(XAVG, WLV, VL, (float*)nullptr, (const float*)nullptr);
    k_gemm512<2><<<dim3(49, 16), dim3(256), 0, stream>>>(VL, WP2, (unsigned short*)nullptr, G, bproj);
    k_fused<<<dim3(392, 8), dim3(512), 0, stream>>>(XW, WH, XH);
    k_gemm_proj<<<dim3(392, 4), dim3(256), 0, stream>>>(XH, WP1, G, out);
}

// Round 7
// 443.611 us; speedup vs baseline: 1.1839x; 1.1839x over previous
//
#include <hip/hip_runtime.h>

// ---------------------------------------------------------------------------
// SpatialAwareSelfAttention  (B=16, H=W=56, C=512, heads=8, window=4x4)
//
// Round 10: revert to R8 bests + fold window-partition/pool INTO k_fused.
//   - k_window_pool and the XW intermediate are eliminated: k_fused reg-
//     stages A directly from f32 x (float4 prefetch 1 chunk ahead, cvt,
//     swizzled ds_write_b128 just-in-time -> single 32KB Abuf).
//   - head==0 blocks emit XAVG as a byproduct (exact f32 window sums via
//     2x shfl_xor; identical arithmetic to the old pool kernel).
//   - LDS 80KB -> 2 blocks/CU (attention epilogue runs in 2 passes of
//     2x32KB sets); cross-block overlap fills the 2-phase barrier stalls.
//   - k_gemm_proj: R8 staged dbuf version (the 390us config). 5 kernels -> 4.
// ---------------------------------------------------------------------------

using bf16x8 = __attribute__((ext_vector_type(8))) short;
using f32x4  = __attribute__((ext_vector_type(4))) float;

#define SCALE 0.044194173824159216f   // 512^-0.5 (full C, per reference)

__device__ __forceinline__ unsigned short f2bf(float f) {
    union { float f; unsigned u; } v; v.f = f;
    unsigned u = v.u;
    return (unsigned short)((u + 0x7fffu + ((u >> 16) & 1u)) >> 16);
}

__device__ __forceinline__ unsigned pk2(float a, float b) {
    return (unsigned)f2bf(a) | ((unsigned)f2bf(b) << 16);
}

__device__ __forceinline__ void gl2lds16(const unsigned short* g, unsigned short* l) {
    __builtin_amdgcn_global_load_lds(
        (const __attribute__((address_space(1))) void*)g,
        (__attribute__((address_space(3))) void*)l, 16, 0, 0);
}

// ---- K0a: weight conversion/repack ----------------------------------------
__global__ void k_prep_weights(const float* __restrict__ wqkv_h,
                               const float* __restrict__ wqkv_l,
                               const float* __restrict__ wproj,
                               unsigned short* __restrict__ WH,
                               unsigned short* __restrict__ WLV,
                               unsigned short* __restrict__ WP1,
                               unsigned short* __restrict__ WP2) {
    int i = blockIdx.x * 256 + threadIdx.x;
    if (i < 786432) {
        WH[i] = f2bf(wqkv_h[i]);              // [1536][512] row-major
    } else {
        int j = i - 786432;
        int r = j >> 18;
        int t = j & 262143;
        int n = t >> 9, k = t & 511;
        if (r == 0)      WLV[t] = f2bf(wqkv_l[(1024 + n) * 512 + k]); // v-rows
        else if (r == 1) WP1[t] = f2bf(wproj[n * 1024 + k]);
        else             WP2[t] = f2bf(wproj[n * 1024 + 512 + k]);
    }
}

// ---- K1: small K=512 GEMM C = A @ B^T, wave tile 16 x (NT*16) -------------
template <int NT>
__global__ void k_gemm512(const unsigned short* __restrict__ A,
                          const unsigned short* __restrict__ Bw,
                          unsigned short* __restrict__ outB,
                          float* __restrict__ outF,
                          const float* __restrict__ bias) {
    int wave = threadIdx.x >> 6, lane = threadIdx.x & 63;
    int quad = lane >> 4, l16 = lane & 15;
    int m0 = blockIdx.x * 64 + wave * 16;
    int n0 = blockIdx.y * (NT * 16);
    f32x4 acc[NT] = {};
    const unsigned short* arow = A + (size_t)(m0 + l16) * 512 + quad * 8;
    for (int kk = 0; kk < 16; ++kk) {
        bf16x8 a = *(const bf16x8*)(arow + kk * 32);
        #pragma unroll
        for (int nt = 0; nt < NT; ++nt) {
            bf16x8 b = *(const bf16x8*)(Bw + (size_t)(n0 + nt * 16 + l16) * 512 + kk * 32 + quad * 8);
            acc[nt] = __builtin_amdgcn_mfma_f32_16x16x32_bf16(a, b, acc[nt], 0, 0, 0);
        }
    }
    #pragma unroll
    for (int nt = 0; nt < NT; ++nt) {
        int col = n0 + nt * 16 + l16;
        float bv = (bias != nullptr) ? bias[col] : 0.f;
        #pragma unroll
        for (int r = 0; r < 4; ++r) {
            int row = m0 + quad * 4 + r;
            if (outF != nullptr) outF[(size_t)row * 512 + col] = acc[nt][r] + bv;
            else                 outB[(size_t)row * 512 + col] = f2bf(acc[nt][r]);
        }
    }
}

// ---- K2 helpers ------------------------------------------------------------
__device__ __forceinline__ void st_row(unsigned short* Ab, int wofs, float4 v0, float4 v1) {
    uint4 pk;
    pk.x = pk2(v0.x, v0.y); pk.y = pk2(v0.z, v0.w);
    pk.z = pk2(v1.x, v1.y); pk.w = pk2(v1.z, v1.w);
    *(uint4*)&Ab[wofs] = pk;
}

__device__ __forceinline__ void xavg_emit(const float4 (&xc)[4][2], int sg,
                                          unsigned short* __restrict__ XAVG,
                                          size_t dofs) {
    float v[8];
    v[0] = xc[0][0].x + xc[1][0].x + xc[2][0].x + xc[3][0].x;
    v[1] = xc[0][0].y + xc[1][0].y + xc[2][0].y + xc[3][0].y;
    v[2] = xc[0][0].z + xc[1][0].z + xc[2][0].z + xc[3][0].z;
    v[3] = xc[0][0].w + xc[1][0].w + xc[2][0].w + xc[3][0].w;
    v[4] = xc[0][1].x + xc[1][1].x + xc[2][1].x + xc[3][1].x;
    v[5] = xc[0][1].y + xc[1][1].y + xc[2][1].y + xc[3][1].y;
    v[6] = xc[0][1].z + xc[1][1].z + xc[2][1].z + xc[3][1].z;
    v[7] = xc[0][1].w + xc[1][1].w + xc[2][1].w + xc[3][1].w;
    #pragma unroll
    for (int c = 0; c < 8; ++c) {
        v[c] += __shfl_xor(v[c], 8);
        v[c] += __shfl_xor(v[c], 16);
    }
    if (sg == 0) {
        uint4 pa;
        pa.x = pk2(v[0] * 0.0625f, v[1] * 0.0625f);
        pa.y = pk2(v[2] * 0.0625f, v[3] * 0.0625f);
        pa.z = pk2(v[4] * 0.0625f, v[5] * 0.0625f);
        pa.w = pk2(v[6] * 0.0625f, v[7] * 0.0625f);
        *(uint4*)&XAVG[dofs] = pa;
    }
}

// ---- K2: fused partition/pool + qkv GEMM (256x192x512) + attention --------
// grid (196, 8) XCD-remapped; 512 threads, 8 waves of M64 x N96
// (mh = wave>>1 M-quarter, nq = wave&1 N-half).
// A: reg-staged from f32 x (prefetch 1 chunk ahead), swizzled ds_write into
// single 32KB Abuf. B: gl2lds-staged dbuf (2x24KB), counted vmcnt(11).
// head==0 blocks also emit XAVG (exact f32 window means).
__global__ void __launch_bounds__(512, 2) k_fused(const float* __restrict__ x,
                                                  const unsigned short* __restrict__ WH,
                                                  unsigned short* __restrict__ XH,
                                                  unsigned short* __restrict__ XAVG) {
    __shared__ __align__(16) char smem[81920];
    // staging: Abuf [256][64] shorts 32KB at 0; Bbuf[2] 24KB at 32768/57344.
    // attention (after K-loop, 2 passes): 2 sets x 32768 B at 0 / 32768:
    //   qs [64][72] 9216 | ks [64][72] 9216 | vts [64][80] 10240 | Ps 4096

    const int tid  = threadIdx.x;
    const int wave = tid >> 6, lane = tid & 63;
    const int quad = lane >> 4, l16 = lane & 15;
    const int mh = wave >> 1, nq = wave & 1;

    // bijective XCD remap (1568 = 8*196): heads of a token-panel consecutive
    // on one XCD -> x panel + whole-WH set pinned in that XCD's L2.
    int id   = blockIdx.y * 196 + blockIdx.x;
    int w_   = (id & 7) * 196 + (id >> 3);
    int tb   = w_ >> 3, head = w_ & 7;
    const int m0 = tb * 256;

    // ---- A source map: thread owns window sw, row-group sg, ch-slice ss ---
    // rows 16*sw + 4*sg + j (j=0..3) are spatially consecutive in x (along W).
    const int sw = tid >> 5, sg = (tid >> 3) & 3, ss = tid & 7;
    const int win_g = tb * 16 + sw;
    int bb = win_g / 196, rem = win_g % 196, wh = rem / 14, ww = rem % 14;
    const float* xbase = x + (size_t)(((bb * 56 + wh * 4 + sg) * 56 + ww * 4) * 512) + ss * 8;
    // swizzled LDS write offsets (shorts): stored unit u at row n holds
    // global unit u^(n&7)  <=>  write global slice ss at unit ss^(n&7).
    int wofs0, wofs1, wofs2, wofs3;
    {
        int r0 = 16 * sw + 4 * sg;
        wofs0 = (r0 + 0) * 64 + ((ss ^ ((r0 + 0) & 7)) * 8);
        wofs1 = (r0 + 1) * 64 + ((ss ^ ((r0 + 1) & 7)) * 8);
        wofs2 = (r0 + 2) * 64 + ((ss ^ ((r0 + 2) & 7)) * 8);
        wofs3 = (r0 + 3) * 64 + ((ss ^ ((r0 + 3) & 7)) * 8);
    }

    // ---- B staging map (unchanged from R8; rule #21 pair) -----------------
    int bof[3];
    #pragma unroll
    for (int i = 0; i < 3; ++i) {
        int u = i * 512 + tid;                 // B unit 0..1535
        int n = u >> 3;                        // qkv row 0..191 (s-major)
        int gu = (u & 7) ^ (n & 7);
        int nrow = (n >> 6) * 512 + head * 64 + (n & 63);
        bof[i] = nrow * 512 + gu * 8;
    }

    f32x4 acc[4][6] = {};   // rows mh*64+mf*16+, cols nq*96+j*16+
    const int sx = l16 & 7;

    float4 xrA[4][2], xrB[4][2];

    // prologue: x(0) -> xrA ; gl2lds B(0) -> Bbuf0
    #pragma unroll
    for (int j = 0; j < 4; ++j) {
        xrA[j][0] = *(const float4*)(xbase + (size_t)j * 512);
        xrA[j][1] = *(const float4*)(xbase + (size_t)j * 512 + 4);
    }
    {
        unsigned short* B0 = (unsigned short*)(smem + 32768);
        #pragma unroll
        for (int i = 0; i < 3; ++i)
            gl2lds16(WH + bof[i], B0 + (i * 512 + wave * 64) * 8);
    }

#define QKV_STEP(CH, XRC, XRN)                                                 \
{                                                                              \
    unsigned short* Ab = (unsigned short*)smem;                                \
    unsigned short* Bb = (unsigned short*)(smem + 32768 + ((CH) & 1) * 24576); \
    /* A(CH): cvt + swizzled ds_write (compiler waits the x loads) */          \
    st_row(Ab, wofs0, XRC[0][0], XRC[0][1]);                                   \
    st_row(Ab, wofs1, XRC[1][0], XRC[1][1]);                                   \
    st_row(Ab, wofs2, XRC[2][0], XRC[2][1]);                                   \
    st_row(Ab, wofs3, XRC[3][0], XRC[3][1]);                                   \
    if (head == 0)                                                             \
        xavg_emit(XRC, sg, XAVG, (size_t)win_g * 512 + (CH) * 64 + ss * 8);    \
    if ((CH) < 7) {                                                            \
        _Pragma("unroll")                                                      \
        for (int j = 0; j < 4; ++j) {                                          \
            XRN[j][0] = *(const float4*)(xbase + (size_t)j * 512 + ((CH) + 1) * 64);     \
            XRN[j][1] = *(const float4*)(xbase + (size_t)j * 512 + ((CH) + 1) * 64 + 4); \
        }                                                                      \
        unsigned short* Bn = (unsigned short*)(smem + 32768 + (((CH) + 1) & 1) * 24576); \
        _Pragma("unroll")                                                      \
        for (int i = 0; i < 3; ++i)                                            \
            gl2lds16(WH + bof[i] + ((CH) + 1) * 64, Bn + (i * 512 + wave * 64) * 8);     \
        asm volatile("s_waitcnt vmcnt(11)" ::: "memory");                      \
    } else {                                                                   \
        asm volatile("s_waitcnt vmcnt(0)" ::: "memory");                       \
    }                                                                          \
    asm volatile("s_waitcnt lgkmcnt(0)" ::: "memory");                         \
    __builtin_amdgcn_s_barrier();                                              \
    _Pragma("unroll")                                                          \
    for (int kk = 0; kk < 2; ++kk) {                                           \
        int su = ((kk * 4 + quad) ^ sx) * 8;                                   \
        bf16x8 a[4], b[6];                                                     \
        _Pragma("unroll")                                                      \
        for (int mf = 0; mf < 4; ++mf)                                         \
            a[mf] = *(const bf16x8*)&Ab[(mh * 64 + mf * 16 + l16) * 64 + su];  \
        _Pragma("unroll")                                                      \
        for (int j = 0; j < 6; ++j)                                            \
            b[j] = *(const bf16x8*)&Bb[(nq * 96 + j * 16 + l16) * 64 + su];    \
        _Pragma("unroll")                                                      \
        for (int mf = 0; mf < 4; ++mf)                                         \
            _Pragma("unroll")                                                  \
            for (int j = 0; j < 6; ++j)                                        \
                acc[mf][j] = __builtin_amdgcn_mfma_f32_16x16x32_bf16(a[mf], b[j], acc[mf][j], 0, 0, 0); \
    }                                                                          \
    asm volatile("s_waitcnt lgkmcnt(0)" ::: "memory");                         \
    __builtin_amdgcn_s_barrier();                                              \
}

    QKV_STEP(0, xrA, xrB)
    QKV_STEP(1, xrB, xrA)
    QKV_STEP(2, xrA, xrB)
    QKV_STEP(3, xrB, xrA)
    QKV_STEP(4, xrA, xrB)
    QKV_STEP(5, xrB, xrA)
    QKV_STEP(6, xrA, xrB)
    QKV_STEP(7, xrB, xrA)
#undef QKV_STEP

    // ---- attention in 2 passes (2 LDS sets of 32KB alias the staging) -----
    #pragma unroll
    for (int pass = 0; pass < 2; ++pass) {
        const int active = (mh >> 1) == pass;   // waves with mh in {2p, 2p+1}
        char* att = smem + (mh & 1) * 32768;
        unsigned short* qs  = (unsigned short*)att;
        unsigned short* ks  = (unsigned short*)(att + 9216);
        unsigned short* vts = (unsigned short*)(att + 18432);
        unsigned short* Ps  = (unsigned short*)(att + 28672);

        if (active) {   // scatter q/k/v^T for this wave's set
            #pragma unroll
            for (int j = 0; j < 6; ++j) {
                int cb = nq * 96 + j * 16;
                #pragma unroll
                for (int mf = 0; mf < 4; ++mf) {
                    #pragma unroll
                    for (int r = 0; r < 4; ++r) {
                        int tok = mf * 16 + quad * 4 + r;   // set-local 0..63
                        unsigned short hv = f2bf(acc[mf][j][r]);
                        if (cb < 64)       qs[tok * 72 + cb + l16] = hv;
                        else if (cb < 128) ks[tok * 72 + (cb - 64) + l16] = hv;
                        else               vts[(cb - 128 + l16) * 80 + tok] = hv;
                    }
                }
            }
        }
        __syncthreads();

        if (active) {
            #pragma unroll
            for (int sub = 0; sub < 2; ++sub) {
                const int lw = nq * 2 + sub;    // window-in-set 0..3
                const int t0 = lw * 16;
                if (lw == 3) {                   // K-pad zeros (wave-local)
                    #pragma unroll
                    for (int i = 0; i < 16; ++i) vts[lane * 80 + 64 + i] = 0;
                }
                {
                    int prow = lane >> 2, pc = 16 + (lane & 3) * 4;
                    #pragma unroll
                    for (int i = 0; i < 4; ++i) Ps[lw * 512 + prow * 32 + pc + i] = 0;
                }
                // S = (q @ k^T) * scale
                f32x4 sacc = {};
                {
                    bf16x8 a0 = *(const bf16x8*)&qs[(t0 + l16) * 72 + quad * 8];
                    bf16x8 b0 = *(const bf16x8*)&ks[(t0 + l16) * 72 + quad * 8];
                    sacc = __builtin_amdgcn_mfma_f32_16x16x32_bf16(a0, b0, sacc, 0, 0, 0);
                    bf16x8 a1 = *(const bf16x8*)&qs[(t0 + l16) * 72 + 32 + quad * 8];
                    bf16x8 b1 = *(const bf16x8*)&ks[(t0 + l16) * 72 + 32 + quad * 8];
                    sacc = __builtin_amdgcn_mfma_f32_16x16x32_bf16(a1, b1, sacc, 0, 0, 0);
                }
                // in-register softmax across the quad's 16 lanes
                float p[4];
                #pragma unroll
                for (int r = 0; r < 4; ++r) {
                    float v = sacc[r] * SCALE;
                    float m = v;
                    m = fmaxf(m, __shfl_xor(m, 1));
                    m = fmaxf(m, __shfl_xor(m, 2));
                    m = fmaxf(m, __shfl_xor(m, 4));
                    m = fmaxf(m, __shfl_xor(m, 8));
                    float e = __expf(v - m);
                    float sm = e;
                    sm += __shfl_xor(sm, 1);
                    sm += __shfl_xor(sm, 2);
                    sm += __shfl_xor(sm, 4);
                    sm += __shfl_xor(sm, 8);
                    p[r] = e / sm;
                }
                #pragma unroll
                for (int r = 0; r < 4; ++r)
                    Ps[lw * 512 + (quad * 4 + r) * 32 + l16] = f2bf(p[r]);
                // y = P @ v (K=16 padded to 32; pad-P zero)
                bf16x8 pa = *(const bf16x8*)&Ps[lw * 512 + l16 * 32 + quad * 8];
                #pragma unroll
                for (int nt = 0; nt < 4; ++nt) {
                    f32x4 y = {};
                    bf16x8 bv = *(const bf16x8*)&vts[(nt * 16 + l16) * 80 + t0 + quad * 8];
                    y = __builtin_amdgcn_mfma_f32_16x16x32_bf16(pa, bv, y, 0, 0, 0);
                    #pragma unroll
                    for (int r = 0; r < 4; ++r)
                        XH[(size_t)(m0 + mh * 64 + t0 + quad * 4 + r) * 512 + head * 64 + nt * 16 + l16] = f2bf(y[r]);
                }
            }
        }
        __syncthreads();
    }
}

// ---- K3: out = XH @ WP1^T + G[win], 128x128 block, wave 64x64 -------------
// grid (392, 4), XCD-remapped; counted-vmcnt dbuf (vmcnt(8)). (R8 version)
__global__ void __launch_bounds__(256, 2) k_gemm_proj(const unsigned short* __restrict__ XH,
                                                      const unsigned short* __restrict__ WP1,
                                                      const float* __restrict__ G,
                                                      float* __restrict__ out) {
    __shared__ __align__(16) char smem[65536];   // 2 x (A 16KB | B 16KB)

    const int wave = threadIdx.x >> 6, lane = threadIdx.x & 63;
    const int quad = lane >> 4, l16 = lane & 15;

    int id = blockIdx.y * 392 + blockIdx.x;
    int s  = id >> 3;
    int xb = (id & 7) * 49 + (s >> 2);
    int yb = s & 3;
    const int m0 = xb * 128, n0 = yb * 128;
    const int wm = (wave >> 1) * 64;
    const int wn = (wave & 1) * 64;

    int aofs[4], bofs[4];
    #pragma unroll
    for (int i = 0; i < 4; ++i) {
        int u = (wave * 4 + i) * 64 + lane;   // unit 0..1023
        int n = u >> 3;                        // row 0..127
        int gu = (lane & 7) ^ (n & 7);
        aofs[i] = (m0 + n) * 512 + gu * 8;
        bofs[i] = (n0 + n) * 512 + gu * 8;
    }

    unsigned short* const bufA[2] = { (unsigned short*)smem,
                                      (unsigned short*)(smem + 32768) };
    unsigned short* const bufB[2] = { (unsigned short*)(smem + 16384),
                                      (unsigned short*)(smem + 32768 + 16384) };

    f32x4 acc[4][4] = {};
    const int sx = l16 & 7;

    #pragma unroll
    for (int i = 0; i < 4; ++i) {
        gl2lds16(XH + aofs[i], bufA[0] + (wave * 4 + i) * 512);
        gl2lds16(WP1 + bofs[i], bufB[0] + (wave * 4 + i) * 512);
    }

    #pragma unroll
    for (int ch = 0; ch < 8; ++ch) {
        if (ch < 7) {
            unsigned short* An = bufA[(ch + 1) & 1];
            unsigned short* Bn = bufB[(ch + 1) & 1];
            #pragma unroll
            for (int i = 0; i < 4; ++i) {
                gl2lds16(XH + aofs[i] + (ch + 1) * 64, An + (wave * 4 + i) * 512);
                gl2lds16(WP1 + bofs[i] + (ch + 1) * 64, Bn + (wave * 4 + i) * 512);
            }
        }
        if (ch < 7) asm volatile("s_waitcnt vmcnt(8)" ::: "memory");
        else        asm volatile("s_waitcnt vmcnt(0)" ::: "memory");
        __builtin_amdgcn_s_barrier();

        unsigned short* As = bufA[ch & 1];
        unsigned short* Bs = bufB[ch & 1];
        #pragma unroll
        for (int kk = 0; kk < 2; ++kk) {
            int su = ((kk * 4 + quad) ^ sx) * 8;
            bf16x8 a[4], b[4];
            #pragma unroll
            for (int mf = 0; mf < 4; ++mf)
                a[mf] = *(const bf16x8*)&As[(wm + mf * 16 + l16) * 64 + su];
            #pragma unroll
            for (int j = 0; j < 4; ++j)
                b[j] = *(const bf16x8*)&Bs[(wn + j * 16 + l16) * 64 + su];
            #pragma unroll
            for (int mf = 0; mf < 4; ++mf)
                #pragma unroll
                for (int j = 0; j < 4; ++j)
                    acc[mf][j] = __builtin_amdgcn_mfma_f32_16x16x32_bf16(a[mf], b[j], acc[mf][j], 0, 0, 0);
        }
        asm volatile("s_waitcnt lgkmcnt(0)" ::: "memory");
        __builtin_amdgcn_s_barrier();
    }

    #pragma unroll
    for (int mf = 0; mf < 4; ++mf) {
        #pragma unroll
        for (int r = 0; r < 4; ++r) {
            int tl  = wm + mf * 16 + quad * 4 + r;   // 0..127
            int gt  = m0 + tl;                        // global token
            int win = gt >> 4, tw = gt & 15;
            int bb = win / 196, rem = win % 196;
            int wh = rem / 14, ww = rem % 14;
            int orow = (bb * 56 + wh * 4 + (tw >> 2)) * 56 + ww * 4 + (tw & 3);
            #pragma unroll
            for (int j = 0; j < 4; ++j) {
                int ncol = n0 + wn + j * 16 + l16;
                out[(size_t)orow * 512 + ncol] = acc[mf][j][r] + G[(size_t)win * 512 + ncol];
            }
        }
    }
}

// ---------------------------------------------------------------------------
extern "C" void kernel_launch(void* const* d_in, const int* in_sizes, int n_in,
                              void* d_out, int out_size, void* d_ws, size_t ws_size,
                              hipStream_t stream) {
    const float* x      = (const float*)d_in[0];
    const float* wqkv_h = (const float*)d_in[1];
    const float* wqkv_l = (const float*)d_in[2];
    const float* wproj  = (const float*)d_in[3];
    const float* bproj  = (const float*)d_in[4];
    float* out = (float*)d_out;

    char* ws = (char*)d_ws;
    unsigned short* WH   = (unsigned short*)(ws + 0);         // 1536*512 bf16
    unsigned short* WLV  = (unsigned short*)(ws + 1572864);   // 512*512
    unsigned short* WP1  = (unsigned short*)(ws + 2097152);   // 512*512
    unsigned short* WP2  = (unsigned short*)(ws + 2621440);   // 512*512
    unsigned short* XAVG = (unsigned short*)(ws + 54525952);  // 3136*512
    unsigned short* VL   = (unsigned short*)(ws + 57737216);  // 3136*512
    float*          G    = (float*)(ws + 60948480);           // 3136*512 f32
    unsigned short* XH   = (unsigned short*)(ws + 67371008);  // 50176*512

    k_prep_weights<<<dim3(6144), dim3(256), 0, stream>>>(wqkv_h, wqkv_l, wproj, WH, WLV, WP1, WP2);
    k_fused<<<dim3(196, 8), dim3(512), 0, stream>>>(x, WH, XH, XAVG);
    k_gemm512<2><<<dim3(49, 16), dim3(256), 0, stream>>>(XAVG, WLV, VL, (float*)nullptr, (const float*)nullptr);
    k_gemm512<2><<<dim3(49, 16), dim3(256), 0, stream>>>(VL, WP2, (unsigned short*)nullptr, G, bproj);
    k_gemm_proj<<<dim3(392, 4), dim3(256), 0, stream>>>(XH, WP1, G, out);
}